// Round 24
// baseline (28.375 us; speedup 1.0000x reference)
//
#include <hip/hip_runtime.h>

// L=32768, N=32, E=H=1, BS=256 -> 4096 rank-1 softmax problems:
//   out_i = sum_j 2^(a'_i k_j) v_j / sum_j 2^(a'_i k_j),  a' = (wq q + bq) log2e.
// No max-subtraction (f32-safe, scale-invariant; validated R5-R23).
//
// R24 = R23 (24.9us) with attn occupancy doubled: 128-thread WG (2 waves) per
// problem -> 8192 waves = 32/CU (was 16/CU, 85% latency-idle). Sort stays
// WAVE-0-ONLY (deterministic, bit-identical); moments use all 128 threads
// (16 segs x 8 contiguous eighth-ranges, shfl-combined); row loop splits BY
// ROWS (wave w owns rows 128w..+127, 2 rows/lane) -> per-wave horner halves,
// per-problem LDS traffic unchanged (avoids R20's duplicated-prologue trap
// and R17's strided-conflict trap).

#define LL    32768
#define NN    32
#define BSZ   256
#define NBLK  (LL / BSZ)
#define NSEG  16
#define LOG2E 1.4426950408889634f
#define LN2   0.6931471805599453f

typedef float v2f __attribute__((ext_vector_type(2)));

// ---------------- Kernel P: projection + transpose (verified R3) ----------
__global__ __launch_bounds__(256) void proj_transpose_kernel(
    const float* __restrict__ q_in, const float* __restrict__ k_in,
    const float* __restrict__ v_in,
    const float* __restrict__ ipw,  const float* __restrict__ ipb,
    float* __restrict__ ws)
{
    __shared__ float sa[32][33], sk[32][33], sv[32][33];
    const int t  = threadIdx.x;
    const int r0 = blockIdx.x * 32;

    const float wq = ipw[0], wk = ipw[1], wv = ipw[2];
    const float bq = ipb[0], bk = ipb[1], bv = ipb[2];

    const int f = r0 * NN + t * 4;     // coalesced: 4 consecutive n of one row
    const float4 q4 = *reinterpret_cast<const float4*>(q_in + f);
    const float4 k4 = *reinterpret_cast<const float4*>(k_in + f);
    const float4 v4 = *reinterpret_cast<const float4*>(v_in + f);

    const int row = t >> 3, nc = (t & 7) * 4;
    sa[row][nc + 0] = fmaf(q4.x, wq, bq) * LOG2E;
    sa[row][nc + 1] = fmaf(q4.y, wq, bq) * LOG2E;
    sa[row][nc + 2] = fmaf(q4.z, wq, bq) * LOG2E;
    sa[row][nc + 3] = fmaf(q4.w, wq, bq) * LOG2E;
    sk[row][nc + 0] = fmaf(k4.x, wk, bk);
    sk[row][nc + 1] = fmaf(k4.y, wk, bk);
    sk[row][nc + 2] = fmaf(k4.z, wk, bk);
    sk[row][nc + 3] = fmaf(k4.w, wk, bk);
    sv[row][nc + 0] = fmaf(v4.x, wv, bv);
    sv[row][nc + 1] = fmaf(v4.y, wv, bv);
    sv[row][nc + 2] = fmaf(v4.z, wv, bv);
    sv[row][nc + 3] = fmaf(v4.w, wv, bv);
    __syncthreads();

    float* __restrict__ A = ws;
    float* __restrict__ K = ws + (size_t)LL * NN;
    float* __restrict__ V = ws + (size_t)2 * LL * NN;
    const int n = t >> 3, j0 = (t & 7) * 4;  // coalesced: 4 consecutive rows

    float4 o;
    o.x = sa[j0 + 0][n]; o.y = sa[j0 + 1][n]; o.z = sa[j0 + 2][n]; o.w = sa[j0 + 3][n];
    *reinterpret_cast<float4*>(A + (size_t)n * LL + r0 + j0) = o;
    o.x = sk[j0 + 0][n]; o.y = sk[j0 + 1][n]; o.z = sk[j0 + 2][n]; o.w = sk[j0 + 3][n];
    *reinterpret_cast<float4*>(K + (size_t)n * LL + r0 + j0) = o;
    o.x = sv[j0 + 0][n]; o.y = sv[j0 + 1][n]; o.z = sv[j0 + 2][n]; o.w = sv[j0 + 3][n];
    *reinterpret_cast<float4*>(V + (size_t)n * LL + r0 + j0) = o;
}

__device__ __forceinline__ v2f horner7(v2f u, float4 f0, float4 f1) {
    v2f h = {f1.w, f1.w};
    h = __builtin_elementwise_fma(h, u, (v2f){f1.z, f1.z});
    h = __builtin_elementwise_fma(h, u, (v2f){f1.y, f1.y});
    h = __builtin_elementwise_fma(h, u, (v2f){f1.x, f1.x});
    h = __builtin_elementwise_fma(h, u, (v2f){f0.w, f0.w});
    h = __builtin_elementwise_fma(h, u, (v2f){f0.z, f0.z});
    h = __builtin_elementwise_fma(h, u, (v2f){f0.y, f0.y});
    h = __builtin_elementwise_fma(h, u, (v2f){f0.x, f0.x});
    return h;
}

// ---------------- Kernel A: 2 waves per problem, rows split ----------------
__global__ __launch_bounds__(128) void attn_kernel(
    const float* __restrict__ ws,
    const float* __restrict__ opw, const float* __restrict__ opb,
    float* __restrict__ out)
{
    const int t    = threadIdx.x;        // 0..127
    const int lane = t & 63;
    const int w    = t >> 6;             // wave 0/1
    const int prob = blockIdx.x;         // 0..4095
    const int blk  = prob & 127;         // XCD-aware numbering (R23-verified)
    const int n    = prob >> 7;

    const float* __restrict__ A = ws;
    const float* __restrict__ K = ws + (size_t)LL * NN;
    const float* __restrict__ V = ws + (size_t)2 * LL * NN;
    const int base = n * LL + blk * BSZ;

    __shared__ alignas(16) float2 skv[BSZ];       // sorted (k, v)
    __shared__ alignas(16) float  mom[NSEG][16];  // D0..7 | N0..7  (/d!)
    __shared__ int   hist[128];
    __shared__ float meta[2];                     // kmn, segw

    // own rows' a: wave w owns rows 128w + 2*lane + {0,1}  (coalesced f2)
    const float2 a2 = *reinterpret_cast<const float2*>(A + base + 128 * w + 2 * lane);

    hist[t] = 0;

    // wave 0 gathers full K/V and owns the sort (deterministic, R23 path)
    float kr[4] = {0.f, 0.f, 0.f, 0.f};
    float vr[4] = {0.f, 0.f, 0.f, 0.f};
    float binv0 = 0.f, kmn0 = 0.f;
    if (w == 0) {
        const float4 kf = *reinterpret_cast<const float4*>(K + base + 4 * lane);
        const float4 vf = *reinterpret_cast<const float4*>(V + base + 4 * lane);
        kr[0] = kf.x; kr[1] = kf.y; kr[2] = kf.z; kr[3] = kf.w;
        vr[0] = vf.x; vr[1] = vf.y; vr[2] = vf.z; vr[3] = vf.w;

        float kmn = fminf(fminf(kr[0], kr[1]), fminf(kr[2], kr[3]));
        float kmx = fmaxf(fmaxf(kr[0], kr[1]), fmaxf(kr[2], kr[3]));
        #pragma unroll
        for (int off = 32; off >= 1; off >>= 1) {
            kmn = fminf(kmn, __shfl_xor(kmn, off));
            kmx = fmaxf(kmx, __shfl_xor(kmx, off));
        }
        const float rng = kmx - kmn;
        binv0 = (rng > 0.f) ? (127.99f / rng) : 0.f;
        kmn0  = kmn;
        if (lane == 0) { meta[0] = kmn; meta[1] = rng * (1.0f / NSEG); }
    }
    __syncthreads();                     // hist zero + meta visible

    int bin[4];
    if (w == 0) {
        #pragma unroll
        for (int r = 0; r < 4; ++r) {
            int b = (int)((kr[r] - kmn0) * binv0);
            bin[r] = (b < 0) ? 0 : ((b > 127) ? 127 : b);
            atomicAdd(&hist[bin[r]], 1);  // wave-private, lane-ordered
        }
    }
    __syncthreads();

    if (w == 0) {
        const int c0 = hist[lane];
        const int c1 = hist[lane + 64];
        int i0 = c0, i1 = c1;
        #pragma unroll
        for (int off = 1; off <= 32; off <<= 1) {
            const int t0 = __shfl_up(i0, off);
            const int t1 = __shfl_up(i1, off);
            if (lane >= off) { i0 += t0; i1 += t1; }
        }
        const int tot0 = __shfl(i0, 63);
        hist[lane]      = i0 - c0;        // exclusive starts
        hist[lane + 64] = i1 - c1 + tot0;
    }
    __syncthreads();

    if (w == 0) {
        #pragma unroll
        for (int r = 0; r < 4; ++r) {
            const int slot = atomicAdd(&hist[bin[r]], 1);
            skv[slot] = make_float2(kr[r], vr[r]);
        }
    }
    __syncthreads();
    // hist[b] = END offset of bin b

    const float kmn  = meta[0];
    const float segw = meta[1];

    // ---- moments: all 128 threads; seg = t>>3, eighth = t&7 (contiguous) ----
    {
        const int s  = t >> 3;              // 0..15
        const int ee = t & 7;
        const int beg0 = (s == 0) ? 0 : hist[8 * s - 1];
        const int end0 = hist[8 * s + 7];
        const int len  = end0 - beg0;
        const int beg  = beg0 + (len * ee) / 8;
        const int end  = beg0 + (len * (ee + 1)) / 8;
        const float cs = kmn + (s + 0.5f) * segw;

        float m0=0.f,m1=0.f,m2=0.f,m3=0.f,m4=0.f,m5=0.f,m6=0.f,m7=0.f;
        float q0=0.f,q1=0.f,q2=0.f,q3=0.f,q4=0.f,q5=0.f,q6=0.f,q7=0.f;
        for (int e = beg; e < end; ++e) {
            const float2 kv = skv[e];
            const float dk = kv.x - cs;
            const float vv = kv.y;
            const float p1 = dk,      p2 = p1 * dk, p3 = p2 * dk;
            const float p4 = p3 * dk, p5 = p4 * dk, p6 = p5 * dk, p7 = p6 * dk;
            m0 += 1.f; m1 += p1; m2 += p2; m3 += p3;
            m4 += p4;  m5 += p5; m6 += p6; m7 += p7;
            q0 += vv;
            q1 = fmaf(vv, p1, q1); q2 = fmaf(vv, p2, q2); q3 = fmaf(vv, p3, q3);
            q4 = fmaf(vv, p4, q4); q5 = fmaf(vv, p5, q5); q6 = fmaf(vv, p6, q6);
            q7 = fmaf(vv, p7, q7);
        }
        // combine 8 eighths (aligned 8-lane groups within one wave)
        #pragma unroll
        for (int off = 1; off <= 4; off <<= 1) {
            m0 += __shfl_xor(m0, off); m1 += __shfl_xor(m1, off);
            m2 += __shfl_xor(m2, off); m3 += __shfl_xor(m3, off);
            m4 += __shfl_xor(m4, off); m5 += __shfl_xor(m5, off);
            m6 += __shfl_xor(m6, off); m7 += __shfl_xor(m7, off);
            q0 += __shfl_xor(q0, off); q1 += __shfl_xor(q1, off);
            q2 += __shfl_xor(q2, off); q3 += __shfl_xor(q3, off);
            q4 += __shfl_xor(q4, off); q5 += __shfl_xor(q5, off);
            q6 += __shfl_xor(q6, off); q7 += __shfl_xor(q7, off);
        }
        const int qq = t & 7;
        if (qq < 4) {
            float4 wv4;
            if (qq == 0)      wv4 = make_float4(m0, m1, m2 * 0.5f, m3 * (1.f/6.f));
            else if (qq == 1) wv4 = make_float4(m4 * (1.f/24.f), m5 * (1.f/120.f),
                                                m6 * (1.f/720.f), m7 * (1.f/5040.f));
            else if (qq == 2) wv4 = make_float4(q0, q1, q2 * 0.5f, q3 * (1.f/6.f));
            else              wv4 = make_float4(q4 * (1.f/24.f), q5 * (1.f/120.f),
                                                q6 * (1.f/720.f), q7 * (1.f/5040.f));
            *reinterpret_cast<float4*>(&mom[s][qq * 4]) = wv4;
        }
    }
    __syncthreads();

    // ---- row loop: wave w owns rows 128w..+127, 2 rows/lane (one v2f) ----
    const v2f u = {a2.x * LN2, a2.y * LN2};
    const float c0s = kmn + 0.5f * segw;

    v2f Ee, g;
    Ee.x = __builtin_amdgcn_exp2f(a2.x * c0s);
    Ee.y = __builtin_amdgcn_exp2f(a2.y * c0s);
    g.x  = __builtin_amdgcn_exp2f(a2.x * segw);
    g.y  = __builtin_amdgcn_exp2f(a2.y * segw);
    const v2f G2 = g * g;
    v2f Eo = Ee * g;

    v2f de = {0.f,0.f}, dd = {0.f,0.f}, ne = {0.f,0.f}, no = {0.f,0.f};

    const float4* __restrict__ M4 = (const float4*)&mom[0][0];  // 4 per seg

    #pragma unroll 4
    for (int s = 0; s < NSEG; s += 2) {
        {   // even segment
            const float4 f0 = M4[s * 4 + 0];
            const float4 f1 = M4[s * 4 + 1];
            const float4 f2 = M4[s * 4 + 2];
            const float4 f3 = M4[s * 4 + 3];
            const v2f hd = horner7(u, f0, f1);
            const v2f hn = horner7(u, f2, f3);
            de = __builtin_elementwise_fma(Ee, hd, de);
            ne = __builtin_elementwise_fma(Ee, hn, ne);
            Ee = Ee * G2;
        }
        {   // odd segment
            const float4 f0 = M4[(s + 1) * 4 + 0];
            const float4 f1 = M4[(s + 1) * 4 + 1];
            const float4 f2 = M4[(s + 1) * 4 + 2];
            const float4 f3 = M4[(s + 1) * 4 + 3];
            const v2f hd = horner7(u, f0, f1);
            const v2f hn = horner7(u, f2, f3);
            dd = __builtin_elementwise_fma(Eo, hd, dd);
            no = __builtin_elementwise_fma(Eo, hn, no);
            Eo = Eo * G2;
        }
    }

    const v2f den = de + dd;
    const v2f num = ne + no;

    const float wo = opw[0], bo = opb[0];
    const int r0 = blk * BSZ + 128 * w + 2 * lane;
    out[(size_t)(r0 + 0) * NN + n] = fmaf(num.x / den.x, wo, bo);
    out[(size_t)(r0 + 1) * NN + n] = fmaf(num.y / den.y, wo, bo);
}

extern "C" void kernel_launch(void* const* d_in, const int* in_sizes, int n_in,
                              void* d_out, int out_size, void* d_ws, size_t ws_size,
                              hipStream_t stream) {
    const float* q   = (const float*)d_in[0];
    const float* k   = (const float*)d_in[1];
    const float* v   = (const float*)d_in[2];
    const float* ipw = (const float*)d_in[3];
    const float* ipb = (const float*)d_in[4];
    const float* opw = (const float*)d_in[5];
    const float* opb = (const float*)d_in[6];
    float* out = (float*)d_out;
    float* ws  = (float*)d_ws;   // needs 3*L*N*4 = 12.6 MB

    proj_transpose_kernel<<<dim3(LL / 32), dim3(256), 0, stream>>>(q, k, v, ipw, ipb, ws);
    attn_kernel<<<dim3(NBLK * NN), dim3(128), 0, stream>>>(ws, opw, opb, out);
}

// Round 25
// 28.217 us; speedup vs baseline: 1.0056x; 1.0056x over previous
//
#include <hip/hip_runtime.h>

// L=32768, N=32, E=H=1, BS=256 -> 4096 rank-1 softmax problems:
//   out_i = sum_j 2^(a'_i k_j) v_j / sum_j 2^(a'_i k_j),  a' = (wq q + bq) log2e.
// No max-subtraction (f32-safe, scale-invariant; validated R5-R24).
//
// R25 = R23 (24.9us best) with TWO problems per single wave (2048 WGs):
//  - coupling-free ILP: every phase interleaves problem A and B, so A's LDS/
//    memory latency is filled by B's instructions (R17/R20/R24 proved cross-
//    wave coupling loses; this keeps the decoupled single-wave structure).
//  - ZERO barriers: single-wave WG, same-wave LDS ordering is program order.
//  - pairing (blk,n) with (blk,n+16): one WG writes 2 columns of the same
//    output lines; sibling WGs stride-128 -> same XCD (R23-verified merge).

#define LL    32768
#define NN    32
#define BSZ   256
#define NBLK  (LL / BSZ)
#define NSEG  16
#define LOG2E 1.4426950408889634f
#define LN2   0.6931471805599453f

typedef float v2f __attribute__((ext_vector_type(2)));

// ---------------- Kernel P: projection + transpose (verified R3) ----------
__global__ __launch_bounds__(256) void proj_transpose_kernel(
    const float* __restrict__ q_in, const float* __restrict__ k_in,
    const float* __restrict__ v_in,
    const float* __restrict__ ipw,  const float* __restrict__ ipb,
    float* __restrict__ ws)
{
    __shared__ float sa[32][33], sk[32][33], sv[32][33];
    const int t  = threadIdx.x;
    const int r0 = blockIdx.x * 32;

    const float wq = ipw[0], wk = ipw[1], wv = ipw[2];
    const float bq = ipb[0], bk = ipb[1], bv = ipb[2];

    const int f = r0 * NN + t * 4;     // coalesced: 4 consecutive n of one row
    const float4 q4 = *reinterpret_cast<const float4*>(q_in + f);
    const float4 k4 = *reinterpret_cast<const float4*>(k_in + f);
    const float4 v4 = *reinterpret_cast<const float4*>(v_in + f);

    const int row = t >> 3, nc = (t & 7) * 4;
    sa[row][nc + 0] = fmaf(q4.x, wq, bq) * LOG2E;
    sa[row][nc + 1] = fmaf(q4.y, wq, bq) * LOG2E;
    sa[row][nc + 2] = fmaf(q4.z, wq, bq) * LOG2E;
    sa[row][nc + 3] = fmaf(q4.w, wq, bq) * LOG2E;
    sk[row][nc + 0] = fmaf(k4.x, wk, bk);
    sk[row][nc + 1] = fmaf(k4.y, wk, bk);
    sk[row][nc + 2] = fmaf(k4.z, wk, bk);
    sk[row][nc + 3] = fmaf(k4.w, wk, bk);
    sv[row][nc + 0] = fmaf(v4.x, wv, bv);
    sv[row][nc + 1] = fmaf(v4.y, wv, bv);
    sv[row][nc + 2] = fmaf(v4.z, wv, bv);
    sv[row][nc + 3] = fmaf(v4.w, wv, bv);
    __syncthreads();

    float* __restrict__ A = ws;
    float* __restrict__ K = ws + (size_t)LL * NN;
    float* __restrict__ V = ws + (size_t)2 * LL * NN;
    const int n = t >> 3, j0 = (t & 7) * 4;  // coalesced: 4 consecutive rows

    float4 o;
    o.x = sa[j0 + 0][n]; o.y = sa[j0 + 1][n]; o.z = sa[j0 + 2][n]; o.w = sa[j0 + 3][n];
    *reinterpret_cast<float4*>(A + (size_t)n * LL + r0 + j0) = o;
    o.x = sk[j0 + 0][n]; o.y = sk[j0 + 1][n]; o.z = sk[j0 + 2][n]; o.w = sk[j0 + 3][n];
    *reinterpret_cast<float4*>(K + (size_t)n * LL + r0 + j0) = o;
    o.x = sv[j0 + 0][n]; o.y = sv[j0 + 1][n]; o.z = sv[j0 + 2][n]; o.w = sv[j0 + 3][n];
    *reinterpret_cast<float4*>(V + (size_t)n * LL + r0 + j0) = o;
}

__device__ __forceinline__ v2f horner7(v2f u, float4 f0, float4 f1) {
    v2f h = {f1.w, f1.w};
    h = __builtin_elementwise_fma(h, u, (v2f){f1.z, f1.z});
    h = __builtin_elementwise_fma(h, u, (v2f){f1.y, f1.y});
    h = __builtin_elementwise_fma(h, u, (v2f){f1.x, f1.x});
    h = __builtin_elementwise_fma(h, u, (v2f){f0.w, f0.w});
    h = __builtin_elementwise_fma(h, u, (v2f){f0.z, f0.z});
    h = __builtin_elementwise_fma(h, u, (v2f){f0.y, f0.y});
    h = __builtin_elementwise_fma(h, u, (v2f){f0.x, f0.x});
    return h;
}

// ---------------- Kernel A: 2 problems per wave, zero barriers ----------
__global__ __launch_bounds__(64) void attn_kernel(
    const float* __restrict__ ws,
    const float* __restrict__ opw, const float* __restrict__ opb,
    float* __restrict__ out)
{
    const int lane = threadIdx.x;        // 0..63, one wave per WG
    const int g    = blockIdx.x;         // 0..2047
    const int blk  = g & 127;            // XCD-aware (R23-verified)
    const int nA   = g >> 7;             // 0..15
    const int nB   = nA + 16;            // 16..31

    const float* __restrict__ A = ws;
    const float* __restrict__ K = ws + (size_t)LL * NN;
    const float* __restrict__ V = ws + (size_t)2 * LL * NN;
    const int baseA = nA * LL + blk * BSZ;
    const int baseB = nB * LL + blk * BSZ;

    __shared__ alignas(16) float2 skv[2][BSZ];       // sorted (k, v)
    __shared__ alignas(16) float  mom[2][NSEG][16];  // D0..7 | N0..7 (/d!)
    __shared__ int hist[2][128];

    // ---- gather both problems (6 loads in flight) ----
    const float4 afA = *reinterpret_cast<const float4*>(A + baseA + 4 * lane);
    const float4 kfA = *reinterpret_cast<const float4*>(K + baseA + 4 * lane);
    const float4 vfA = *reinterpret_cast<const float4*>(V + baseA + 4 * lane);
    const float4 afB = *reinterpret_cast<const float4*>(A + baseB + 4 * lane);
    const float4 kfB = *reinterpret_cast<const float4*>(K + baseB + 4 * lane);
    const float4 vfB = *reinterpret_cast<const float4*>(V + baseB + 4 * lane);
    float aA[4]  = {afA.x, afA.y, afA.z, afA.w};
    float krA[4] = {kfA.x, kfA.y, kfA.z, kfA.w};
    float vrA[4] = {vfA.x, vfA.y, vfA.z, vfA.w};
    float aB[4]  = {afB.x, afB.y, afB.z, afB.w};
    float krB[4] = {kfB.x, kfB.y, kfB.z, kfB.w};
    float vrB[4] = {vfB.x, vfB.y, vfB.z, vfB.w};

    // ---- wave kmin/kmax, both problems interleaved ----
    float kmnA = fminf(fminf(krA[0], krA[1]), fminf(krA[2], krA[3]));
    float kmxA = fmaxf(fmaxf(krA[0], krA[1]), fmaxf(krA[2], krA[3]));
    float kmnB = fminf(fminf(krB[0], krB[1]), fminf(krB[2], krB[3]));
    float kmxB = fmaxf(fmaxf(krB[0], krB[1]), fmaxf(krB[2], krB[3]));
    #pragma unroll
    for (int off = 32; off >= 1; off >>= 1) {
        kmnA = fminf(kmnA, __shfl_xor(kmnA, off));
        kmxA = fmaxf(kmxA, __shfl_xor(kmxA, off));
        kmnB = fminf(kmnB, __shfl_xor(kmnB, off));
        kmxB = fmaxf(kmxB, __shfl_xor(kmxB, off));
    }
    const float rngA  = kmxA - kmnA;
    const float rngB  = kmxB - kmnB;
    const float binvA = (rngA > 0.f) ? (127.99f / rngA) : 0.f;
    const float binvB = (rngB > 0.f) ? (127.99f / rngB) : 0.f;
    const float segwA = rngA * (1.0f / NSEG);
    const float segwB = rngB * (1.0f / NSEG);

    // ---- counting sort x2 (no barriers: single-wave LDS ordering) ----
    hist[0][lane]      = 0;
    hist[0][lane + 64] = 0;
    hist[1][lane]      = 0;
    hist[1][lane + 64] = 0;

    int binA[4], binB[4];
    #pragma unroll
    for (int r = 0; r < 4; ++r) {
        int bA = (int)((krA[r] - kmnA) * binvA);
        int bB = (int)((krB[r] - kmnB) * binvB);
        binA[r] = (bA < 0) ? 0 : ((bA > 127) ? 127 : bA);
        binB[r] = (bB < 0) ? 0 : ((bB > 127) ? 127 : bB);
        atomicAdd(&hist[0][binA[r]], 1);   // wave-private, lane-ordered
        atomicAdd(&hist[1][binB[r]], 1);
    }

    {   // exclusive scans (A and B interleaved in one shfl chain)
        const int cA0 = hist[0][lane];
        const int cA1 = hist[0][lane + 64];
        const int cB0 = hist[1][lane];
        const int cB1 = hist[1][lane + 64];
        int iA0 = cA0, iA1 = cA1, iB0 = cB0, iB1 = cB1;
        #pragma unroll
        for (int off = 1; off <= 32; off <<= 1) {
            const int tA0 = __shfl_up(iA0, off);
            const int tA1 = __shfl_up(iA1, off);
            const int tB0 = __shfl_up(iB0, off);
            const int tB1 = __shfl_up(iB1, off);
            if (lane >= off) { iA0 += tA0; iA1 += tA1; iB0 += tB0; iB1 += tB1; }
        }
        const int totA0 = __shfl(iA0, 63);
        const int totB0 = __shfl(iB0, 63);
        hist[0][lane]      = iA0 - cA0;
        hist[0][lane + 64] = iA1 - cA1 + totA0;
        hist[1][lane]      = iB0 - cB0;
        hist[1][lane + 64] = iB1 - cB1 + totB0;
    }

    #pragma unroll
    for (int r = 0; r < 4; ++r) {
        const int sA = atomicAdd(&hist[0][binA[r]], 1);
        skv[0][sA] = make_float2(krA[r], vrA[r]);
        const int sB = atomicAdd(&hist[1][binB[r]], 1);
        skv[1][sB] = make_float2(krB[r], vrB[r]);
    }
    // hist[p][b] = END offset of bin b

    // ---- moments: 4 lanes/segment, contiguous quarters; A then B ----
    {
        const int s  = lane >> 2;           // segment 0..15
        const int qq = lane & 3;            // quarter 0..3
        const float csA = kmnA + (s + 0.5f) * segwA;
        const float csB = kmnB + (s + 0.5f) * segwB;

        #pragma unroll
        for (int p = 0; p < 2; ++p) {
            const float cs = p ? csB : csA;
            const int beg0 = (s == 0) ? 0 : hist[p][8 * s - 1];
            const int end0 = hist[p][8 * s + 7];
            const int len  = end0 - beg0;
            const int beg  = beg0 + (len * qq) / 4;
            const int end  = beg0 + (len * (qq + 1)) / 4;

            float m0=0.f,m1=0.f,m2=0.f,m3=0.f,m4=0.f,m5=0.f,m6=0.f,m7=0.f;
            float q0=0.f,q1=0.f,q2=0.f,q3=0.f,q4=0.f,q5=0.f,q6=0.f,q7=0.f;
            for (int e = beg; e < end; ++e) {
                const float2 kv = skv[p][e];
                const float dk = kv.x - cs;
                const float vv = kv.y;
                const float p1 = dk,      p2 = p1 * dk, p3 = p2 * dk;
                const float p4 = p3 * dk, p5 = p4 * dk, p6 = p5 * dk, p7 = p6 * dk;
                m0 += 1.f; m1 += p1; m2 += p2; m3 += p3;
                m4 += p4;  m5 += p5; m6 += p6; m7 += p7;
                q0 += vv;
                q1 = fmaf(vv, p1, q1); q2 = fmaf(vv, p2, q2); q3 = fmaf(vv, p3, q3);
                q4 = fmaf(vv, p4, q4); q5 = fmaf(vv, p5, q5); q6 = fmaf(vv, p6, q6);
                q7 = fmaf(vv, p7, q7);
            }
            #pragma unroll
            for (int off = 1; off <= 2; off <<= 1) {
                m0 += __shfl_xor(m0, off); m1 += __shfl_xor(m1, off);
                m2 += __shfl_xor(m2, off); m3 += __shfl_xor(m3, off);
                m4 += __shfl_xor(m4, off); m5 += __shfl_xor(m5, off);
                m6 += __shfl_xor(m6, off); m7 += __shfl_xor(m7, off);
                q0 += __shfl_xor(q0, off); q1 += __shfl_xor(q1, off);
                q2 += __shfl_xor(q2, off); q3 += __shfl_xor(q3, off);
                q4 += __shfl_xor(q4, off); q5 += __shfl_xor(q5, off);
                q6 += __shfl_xor(q6, off); q7 += __shfl_xor(q7, off);
            }
            float4 wv4;
            if (qq == 0)      wv4 = make_float4(m0, m1, m2 * 0.5f, m3 * (1.f/6.f));
            else if (qq == 1) wv4 = make_float4(m4 * (1.f/24.f), m5 * (1.f/120.f),
                                                m6 * (1.f/720.f), m7 * (1.f/5040.f));
            else if (qq == 2) wv4 = make_float4(q0, q1, q2 * 0.5f, q3 * (1.f/6.f));
            else              wv4 = make_float4(q4 * (1.f/24.f), q5 * (1.f/120.f),
                                                q6 * (1.f/720.f), q7 * (1.f/5040.f));
            *reinterpret_cast<float4*>(&mom[p][s][qq * 4]) = wv4;
        }
    }

    // ---- fused row loop: 4 rows/thread per problem, A/B interleaved ----
    const v2f uA01 = {aA[0] * LN2, aA[1] * LN2};
    const v2f uA23 = {aA[2] * LN2, aA[3] * LN2};
    const v2f uB01 = {aB[0] * LN2, aB[1] * LN2};
    const v2f uB23 = {aB[2] * LN2, aB[3] * LN2};
    const float c0A = kmnA + 0.5f * segwA;
    const float c0B = kmnB + 0.5f * segwB;

    v2f EeA01, EeA23, gA01, gA23, EeB01, EeB23, gB01, gB23;
    EeA01.x = __builtin_amdgcn_exp2f(aA[0] * c0A);
    EeA01.y = __builtin_amdgcn_exp2f(aA[1] * c0A);
    EeA23.x = __builtin_amdgcn_exp2f(aA[2] * c0A);
    EeA23.y = __builtin_amdgcn_exp2f(aA[3] * c0A);
    gA01.x  = __builtin_amdgcn_exp2f(aA[0] * segwA);
    gA01.y  = __builtin_amdgcn_exp2f(aA[1] * segwA);
    gA23.x  = __builtin_amdgcn_exp2f(aA[2] * segwA);
    gA23.y  = __builtin_amdgcn_exp2f(aA[3] * segwA);
    EeB01.x = __builtin_amdgcn_exp2f(aB[0] * c0B);
    EeB01.y = __builtin_amdgcn_exp2f(aB[1] * c0B);
    EeB23.x = __builtin_amdgcn_exp2f(aB[2] * c0B);
    EeB23.y = __builtin_amdgcn_exp2f(aB[3] * c0B);
    gB01.x  = __builtin_amdgcn_exp2f(aB[0] * segwB);
    gB01.y  = __builtin_amdgcn_exp2f(aB[1] * segwB);
    gB23.x  = __builtin_amdgcn_exp2f(aB[2] * segwB);
    gB23.y  = __builtin_amdgcn_exp2f(aB[3] * segwB);
    const v2f G2A01 = gA01 * gA01, G2A23 = gA23 * gA23;
    const v2f G2B01 = gB01 * gB01, G2B23 = gB23 * gB23;
    v2f EoA01 = EeA01 * gA01, EoA23 = EeA23 * gA23;
    v2f EoB01 = EeB01 * gB01, EoB23 = EeB23 * gB23;

    v2f deA01 = {0.f,0.f}, doA01 = {0.f,0.f}, deA23 = {0.f,0.f}, doA23 = {0.f,0.f};
    v2f neA01 = {0.f,0.f}, noA01 = {0.f,0.f}, neA23 = {0.f,0.f}, noA23 = {0.f,0.f};
    v2f deB01 = {0.f,0.f}, doB01 = {0.f,0.f}, deB23 = {0.f,0.f}, doB23 = {0.f,0.f};
    v2f neB01 = {0.f,0.f}, noB01 = {0.f,0.f}, neB23 = {0.f,0.f}, noB23 = {0.f,0.f};

    const float4* __restrict__ MA = (const float4*)&mom[0][0][0];
    const float4* __restrict__ MB = (const float4*)&mom[1][0][0];

    #pragma unroll 2
    for (int s = 0; s < NSEG; s += 2) {
        {   // even segment, A then B
            const float4 a0 = MA[s*4+0], a1 = MA[s*4+1], a2 = MA[s*4+2], a3 = MA[s*4+3];
            const float4 b0 = MB[s*4+0], b1 = MB[s*4+1], b2 = MB[s*4+2], b3 = MB[s*4+3];
            deA01 = __builtin_elementwise_fma(EeA01, horner7(uA01, a0, a1), deA01);
            neA01 = __builtin_elementwise_fma(EeA01, horner7(uA01, a2, a3), neA01);
            deA23 = __builtin_elementwise_fma(EeA23, horner7(uA23, a0, a1), deA23);
            neA23 = __builtin_elementwise_fma(EeA23, horner7(uA23, a2, a3), neA23);
            deB01 = __builtin_elementwise_fma(EeB01, horner7(uB01, b0, b1), deB01);
            neB01 = __builtin_elementwise_fma(EeB01, horner7(uB01, b2, b3), neB01);
            deB23 = __builtin_elementwise_fma(EeB23, horner7(uB23, b0, b1), deB23);
            neB23 = __builtin_elementwise_fma(EeB23, horner7(uB23, b2, b3), neB23);
            EeA01 = EeA01 * G2A01; EeA23 = EeA23 * G2A23;
            EeB01 = EeB01 * G2B01; EeB23 = EeB23 * G2B23;
        }
        {   // odd segment, A then B
            const float4 a0 = MA[(s+1)*4+0], a1 = MA[(s+1)*4+1], a2 = MA[(s+1)*4+2], a3 = MA[(s+1)*4+3];
            const float4 b0 = MB[(s+1)*4+0], b1 = MB[(s+1)*4+1], b2 = MB[(s+1)*4+2], b3 = MB[(s+1)*4+3];
            doA01 = __builtin_elementwise_fma(EoA01, horner7(uA01, a0, a1), doA01);
            noA01 = __builtin_elementwise_fma(EoA01, horner7(uA01, a2, a3), noA01);
            doA23 = __builtin_elementwise_fma(EoA23, horner7(uA23, a0, a1), doA23);
            noA23 = __builtin_elementwise_fma(EoA23, horner7(uA23, a2, a3), noA23);
            doB01 = __builtin_elementwise_fma(EoB01, horner7(uB01, b0, b1), doB01);
            noB01 = __builtin_elementwise_fma(EoB01, horner7(uB01, b2, b3), noB01);
            doB23 = __builtin_elementwise_fma(EoB23, horner7(uB23, b0, b1), doB23);
            noB23 = __builtin_elementwise_fma(EoB23, horner7(uB23, b2, b3), noB23);
            EoA01 = EoA01 * G2A01; EoA23 = EoA23 * G2A23;
            EoB01 = EoB01 * G2B01; EoB23 = EoB23 * G2B23;
        }
    }

    const v2f dA01 = deA01 + doA01, dA23 = deA23 + doA23;
    const v2f nAx01 = neA01 + noA01, nAx23 = neA23 + noA23;
    const v2f dB01 = deB01 + doB01, dB23 = deB23 + doB23;
    const v2f nBx01 = neB01 + noB01, nBx23 = neB23 + noB23;

    const float wo = opw[0], bo = opb[0];
    const int rbase = blk * BSZ + 4 * lane;
    out[(size_t)(rbase + 0) * NN + nA] = fmaf(nAx01.x / dA01.x, wo, bo);
    out[(size_t)(rbase + 1) * NN + nA] = fmaf(nAx01.y / dA01.y, wo, bo);
    out[(size_t)(rbase + 2) * NN + nA] = fmaf(nAx23.x / dA23.x, wo, bo);
    out[(size_t)(rbase + 3) * NN + nA] = fmaf(nAx23.y / dA23.y, wo, bo);
    out[(size_t)(rbase + 0) * NN + nB] = fmaf(nBx01.x / dB01.x, wo, bo);
    out[(size_t)(rbase + 1) * NN + nB] = fmaf(nBx01.y / dB01.y, wo, bo);
    out[(size_t)(rbase + 2) * NN + nB] = fmaf(nBx23.x / dB23.x, wo, bo);
    out[(size_t)(rbase + 3) * NN + nB] = fmaf(nBx23.y / dB23.y, wo, bo);
}

extern "C" void kernel_launch(void* const* d_in, const int* in_sizes, int n_in,
                              void* d_out, int out_size, void* d_ws, size_t ws_size,
                              hipStream_t stream) {
    const float* q   = (const float*)d_in[0];
    const float* k   = (const float*)d_in[1];
    const float* v   = (const float*)d_in[2];
    const float* ipw = (const float*)d_in[3];
    const float* ipb = (const float*)d_in[4];
    const float* opw = (const float*)d_in[5];
    const float* opb = (const float*)d_in[6];
    float* out = (float*)d_out;
    float* ws  = (float*)d_ws;   // needs 3*L*N*4 = 12.6 MB

    proj_transpose_kernel<<<dim3(LL / 32), dim3(256), 0, stream>>>(q, k, v, ipw, ipb, ws);
    attn_kernel<<<dim3(NBLK * NN / 2), dim3(64), 0, stream>>>(ws, opw, opb, out);
}

// Round 26
// 22.942 us; speedup vs baseline: 1.2368x; 1.2299x over previous
//
#include <hip/hip_runtime.h>

// L=32768, N=32, E=H=1, BS=256 -> 4096 rank-1 softmax problems:
//   out_i = sum_j 2^(a'_i k_j) v_j / sum_j 2^(a'_i k_j),  a' = (wq q + bq) log2e.
// No max-subtraction (f32-safe, scale-invariant; validated R5-R25).
//
// R26 = R23 (24.9us best) with ONE change: prepass grid remapped so the
// producer of block bb's plane data lands on XCD bb%8 -- the SAME XCD as the
// attn consumer (R23 mapping: blk = prob&127 -> XCD blk%8). Previously the 8
// prepass WGs of a block round-robined over all 8 XCDs, so attn's 4 dependent
// gather loads systematically missed the producer L2 (~900cy HBM latency
// each; the longest links in the 80%-idle latency wall). Per-XCD working set
// ~48KB << 4MB L2. Both kernels' math is bit-identical to R23.

#define LL    32768
#define NN    32
#define BSZ   256
#define NBLK  (LL / BSZ)
#define NSEG  16
#define LOG2E 1.4426950408889634f
#define LN2   0.6931471805599453f

typedef float v2f __attribute__((ext_vector_type(2)));

// ---------------- Kernel P: projection + transpose (verified R3) ----------
// Grid 1024; WG g handles rows r0 = (g&127)*256 + (g>>7)*32 so that all 8
// chunks of block bb sit on XCD bb%8 (128 == 0 mod 8).
__global__ __launch_bounds__(256) void proj_transpose_kernel(
    const float* __restrict__ q_in, const float* __restrict__ k_in,
    const float* __restrict__ v_in,
    const float* __restrict__ ipw,  const float* __restrict__ ipb,
    float* __restrict__ ws)
{
    __shared__ float sa[32][33], sk[32][33], sv[32][33];
    const int t   = threadIdx.x;
    const int bb  = blockIdx.x & 127;   // 256-row block
    const int sub = blockIdx.x >> 7;    // 32-row chunk within block
    const int r0  = bb * 256 + sub * 32;

    const float wq = ipw[0], wk = ipw[1], wv = ipw[2];
    const float bq = ipb[0], bk = ipb[1], bv = ipb[2];

    const int f = r0 * NN + t * 4;     // coalesced: 4 consecutive n of one row
    const float4 q4 = *reinterpret_cast<const float4*>(q_in + f);
    const float4 k4 = *reinterpret_cast<const float4*>(k_in + f);
    const float4 v4 = *reinterpret_cast<const float4*>(v_in + f);

    const int row = t >> 3, nc = (t & 7) * 4;
    sa[row][nc + 0] = fmaf(q4.x, wq, bq) * LOG2E;
    sa[row][nc + 1] = fmaf(q4.y, wq, bq) * LOG2E;
    sa[row][nc + 2] = fmaf(q4.z, wq, bq) * LOG2E;
    sa[row][nc + 3] = fmaf(q4.w, wq, bq) * LOG2E;
    sk[row][nc + 0] = fmaf(k4.x, wk, bk);
    sk[row][nc + 1] = fmaf(k4.y, wk, bk);
    sk[row][nc + 2] = fmaf(k4.z, wk, bk);
    sk[row][nc + 3] = fmaf(k4.w, wk, bk);
    sv[row][nc + 0] = fmaf(v4.x, wv, bv);
    sv[row][nc + 1] = fmaf(v4.y, wv, bv);
    sv[row][nc + 2] = fmaf(v4.z, wv, bv);
    sv[row][nc + 3] = fmaf(v4.w, wv, bv);
    __syncthreads();

    float* __restrict__ A = ws;
    float* __restrict__ K = ws + (size_t)LL * NN;
    float* __restrict__ V = ws + (size_t)2 * LL * NN;
    const int n = t >> 3, j0 = (t & 7) * 4;  // coalesced: 4 consecutive rows

    float4 o;
    o.x = sa[j0 + 0][n]; o.y = sa[j0 + 1][n]; o.z = sa[j0 + 2][n]; o.w = sa[j0 + 3][n];
    *reinterpret_cast<float4*>(A + (size_t)n * LL + r0 + j0) = o;
    o.x = sk[j0 + 0][n]; o.y = sk[j0 + 1][n]; o.z = sk[j0 + 2][n]; o.w = sk[j0 + 3][n];
    *reinterpret_cast<float4*>(K + (size_t)n * LL + r0 + j0) = o;
    o.x = sv[j0 + 0][n]; o.y = sv[j0 + 1][n]; o.z = sv[j0 + 2][n]; o.w = sv[j0 + 3][n];
    *reinterpret_cast<float4*>(V + (size_t)n * LL + r0 + j0) = o;
}

__device__ __forceinline__ v2f horner7(v2f u, float4 f0, float4 f1) {
    // coefficients c0..c7 = {f0.x..w, f1.x..w}
    v2f h = {f1.w, f1.w};
    h = __builtin_elementwise_fma(h, u, (v2f){f1.z, f1.z});
    h = __builtin_elementwise_fma(h, u, (v2f){f1.y, f1.y});
    h = __builtin_elementwise_fma(h, u, (v2f){f1.x, f1.x});
    h = __builtin_elementwise_fma(h, u, (v2f){f0.w, f0.w});
    h = __builtin_elementwise_fma(h, u, (v2f){f0.z, f0.z});
    h = __builtin_elementwise_fma(h, u, (v2f){f0.y, f0.y});
    h = __builtin_elementwise_fma(h, u, (v2f){f0.x, f0.x});
    return h;
}

// ---------------- Kernel A: segmented-Taylor fused (R23, unchanged) --------
__global__ __launch_bounds__(64) void attn_kernel(
    const float* __restrict__ ws,
    const float* __restrict__ opw, const float* __restrict__ opb,
    float* __restrict__ out)
{
    const int lane = threadIdx.x;        // 0..63, one wave per WG
    const int prob = blockIdx.x;         // 0..4095
    const int blk  = prob & 127;         // XCD-aware: siblings same XCD
    const int n    = prob >> 7;

    const float* __restrict__ A = ws;
    const float* __restrict__ K = ws + (size_t)LL * NN;
    const float* __restrict__ V = ws + (size_t)2 * LL * NN;
    const int base = n * LL + blk * BSZ;

    __shared__ alignas(16) float2 skv[BSZ];       // sorted (k, v)
    __shared__ alignas(16) float  mom[NSEG][16];  // D0..7 | N0..7  (/d!)
    __shared__ int hist[128];

    // ---- coalesced gather: lane owns rows 4*lane + {0..3} ----
    const float4 af = *reinterpret_cast<const float4*>(A + base + 4 * lane);
    const float4 kf = *reinterpret_cast<const float4*>(K + base + 4 * lane);
    const float4 vf = *reinterpret_cast<const float4*>(V + base + 4 * lane);
    float a[4]  = {af.x, af.y, af.z, af.w};   // already * LOG2E
    float kr[4] = {kf.x, kf.y, kf.z, kf.w};
    float vr[4] = {vf.x, vf.y, vf.z, vf.w};

    // wave kmin/kmax
    float kmn = fminf(fminf(kr[0], kr[1]), fminf(kr[2], kr[3]));
    float kmx = fmaxf(fmaxf(kr[0], kr[1]), fmaxf(kr[2], kr[3]));
    #pragma unroll
    for (int off = 32; off >= 1; off >>= 1) {
        kmn = fminf(kmn, __shfl_xor(kmn, off));
        kmx = fmaxf(kmx, __shfl_xor(kmx, off));
    }
    const float rng  = kmx - kmn;
    const float binv = (rng > 0.f) ? (127.99f / rng) : 0.f;
    const float segw = rng * (1.0f / NSEG);

    // ---- counting sort by 7-bit quantized k (verified R13-R25) ----
    hist[lane]      = 0;
    hist[lane + 64] = 0;
    __syncthreads();

    int bin[4];
    #pragma unroll
    for (int r = 0; r < 4; ++r) {
        int b = (int)((kr[r] - kmn) * binv);
        bin[r] = (b < 0) ? 0 : ((b > 127) ? 127 : b);
        atomicAdd(&hist[bin[r]], 1);      // wave-private, lane-ordered
    }
    __syncthreads();

    {
        const int c0 = hist[lane];
        const int c1 = hist[lane + 64];
        int i0 = c0, i1 = c1;
        #pragma unroll
        for (int off = 1; off <= 32; off <<= 1) {
            const int t0 = __shfl_up(i0, off);
            const int t1 = __shfl_up(i1, off);
            if (lane >= off) { i0 += t0; i1 += t1; }
        }
        const int tot0 = __shfl(i0, 63);
        hist[lane]      = i0 - c0;        // exclusive starts
        hist[lane + 64] = i1 - c1 + tot0;
    }
    __syncthreads();

    #pragma unroll
    for (int r = 0; r < 4; ++r) {
        const int slot = atomicAdd(&hist[bin[r]], 1);
        skv[slot] = make_float2(kr[r], vr[r]);
    }
    __syncthreads();
    // hist[b] = END offset of bin b

    // ---- moments: 4 lanes per segment (contiguous quarter-ranges) ----
    {
        const int s  = lane >> 2;           // segment 0..15
        const int qq = lane & 3;            // quarter 0..3
        const int beg0 = (s == 0) ? 0 : hist[8 * s - 1];
        const int end0 = hist[8 * s + 7];
        const int len  = end0 - beg0;
        const int beg  = beg0 + (len * qq) / 4;
        const int end  = beg0 + (len * (qq + 1)) / 4;
        const float cs = kmn + (s + 0.5f) * segw;

        float m0=0.f,m1=0.f,m2=0.f,m3=0.f,m4=0.f,m5=0.f,m6=0.f,m7=0.f;
        float q0=0.f,q1=0.f,q2=0.f,q3=0.f,q4=0.f,q5=0.f,q6=0.f,q7=0.f;
        for (int e = beg; e < end; ++e) {
            const float2 kv = skv[e];
            const float dk = kv.x - cs;
            const float vv = kv.y;
            const float p1 = dk,      p2 = p1 * dk, p3 = p2 * dk;
            const float p4 = p3 * dk, p5 = p4 * dk, p6 = p5 * dk, p7 = p6 * dk;
            m0 += 1.f; m1 += p1; m2 += p2; m3 += p3;
            m4 += p4;  m5 += p5; m6 += p6; m7 += p7;
            q0 += vv;
            q1 = fmaf(vv, p1, q1); q2 = fmaf(vv, p2, q2); q3 = fmaf(vv, p3, q3);
            q4 = fmaf(vv, p4, q4); q5 = fmaf(vv, p5, q5); q6 = fmaf(vv, p6, q6);
            q7 = fmaf(vv, p7, q7);
        }
        // combine 4 quarters (lanes 4s..4s+3)
        #pragma unroll
        for (int off = 1; off <= 2; off <<= 1) {
            m0 += __shfl_xor(m0, off); m1 += __shfl_xor(m1, off);
            m2 += __shfl_xor(m2, off); m3 += __shfl_xor(m3, off);
            m4 += __shfl_xor(m4, off); m5 += __shfl_xor(m5, off);
            m6 += __shfl_xor(m6, off); m7 += __shfl_xor(m7, off);
            q0 += __shfl_xor(q0, off); q1 += __shfl_xor(q1, off);
            q2 += __shfl_xor(q2, off); q3 += __shfl_xor(q3, off);
            q4 += __shfl_xor(q4, off); q5 += __shfl_xor(q5, off);
            q6 += __shfl_xor(q6, off); q7 += __shfl_xor(q7, off);
        }
        // each lane writes one float4 (qq selects which)
        float4 wv4;
        if (qq == 0)      wv4 = make_float4(m0, m1, m2 * 0.5f, m3 * (1.f/6.f));
        else if (qq == 1) wv4 = make_float4(m4 * (1.f/24.f), m5 * (1.f/120.f),
                                            m6 * (1.f/720.f), m7 * (1.f/5040.f));
        else if (qq == 2) wv4 = make_float4(q0, q1, q2 * 0.5f, q3 * (1.f/6.f));
        else              wv4 = make_float4(q4 * (1.f/24.f), q5 * (1.f/120.f),
                                            q6 * (1.f/720.f), q7 * (1.f/5040.f));
        *reinterpret_cast<float4*>(&mom[s][qq * 4]) = wv4;
    }
    __syncthreads();

    // ---- row loop: 4 rows/thread, E-recurrence (2 chains), deg-7 Horner ----
    const v2f u01 = {a[0] * LN2, a[1] * LN2};
    const v2f u23 = {a[2] * LN2, a[3] * LN2};
    const float c0s = kmn + 0.5f * segw;

    v2f Ee01, Ee23, g01, g23;
    Ee01.x = __builtin_amdgcn_exp2f(a[0] * c0s);
    Ee01.y = __builtin_amdgcn_exp2f(a[1] * c0s);
    Ee23.x = __builtin_amdgcn_exp2f(a[2] * c0s);
    Ee23.y = __builtin_amdgcn_exp2f(a[3] * c0s);
    g01.x  = __builtin_amdgcn_exp2f(a[0] * segw);
    g01.y  = __builtin_amdgcn_exp2f(a[1] * segw);
    g23.x  = __builtin_amdgcn_exp2f(a[2] * segw);
    g23.y  = __builtin_amdgcn_exp2f(a[3] * segw);
    const v2f G2_01 = g01 * g01;
    const v2f G2_23 = g23 * g23;
    v2f Eo01 = Ee01 * g01;
    v2f Eo23 = Ee23 * g23;

    v2f de01 = {0.f,0.f}, do01 = {0.f,0.f}, de23 = {0.f,0.f}, do23 = {0.f,0.f};
    v2f ne01 = {0.f,0.f}, no01 = {0.f,0.f}, ne23 = {0.f,0.f}, no23 = {0.f,0.f};

    const float4* __restrict__ M4 = (const float4*)&mom[0][0];  // 4 per seg

    #pragma unroll 4
    for (int s = 0; s < NSEG; s += 2) {
        {   // even segment
            const float4 f0 = M4[s * 4 + 0];
            const float4 f1 = M4[s * 4 + 1];
            const float4 f2 = M4[s * 4 + 2];
            const float4 f3 = M4[s * 4 + 3];
            const v2f hd01 = horner7(u01, f0, f1);
            const v2f hn01 = horner7(u01, f2, f3);
            const v2f hd23 = horner7(u23, f0, f1);
            const v2f hn23 = horner7(u23, f2, f3);
            de01 = __builtin_elementwise_fma(Ee01, hd01, de01);
            ne01 = __builtin_elementwise_fma(Ee01, hn01, ne01);
            de23 = __builtin_elementwise_fma(Ee23, hd23, de23);
            ne23 = __builtin_elementwise_fma(Ee23, hn23, ne23);
            Ee01 = Ee01 * G2_01;
            Ee23 = Ee23 * G2_23;
        }
        {   // odd segment
            const float4 f0 = M4[(s + 1) * 4 + 0];
            const float4 f1 = M4[(s + 1) * 4 + 1];
            const float4 f2 = M4[(s + 1) * 4 + 2];
            const float4 f3 = M4[(s + 1) * 4 + 3];
            const v2f hd01 = horner7(u01, f0, f1);
            const v2f hn01 = horner7(u01, f2, f3);
            const v2f hd23 = horner7(u23, f0, f1);
            const v2f hn23 = horner7(u23, f2, f3);
            do01 = __builtin_elementwise_fma(Eo01, hd01, do01);
            no01 = __builtin_elementwise_fma(Eo01, hn01, no01);
            do23 = __builtin_elementwise_fma(Eo23, hd23, do23);
            no23 = __builtin_elementwise_fma(Eo23, hn23, no23);
            Eo01 = Eo01 * G2_01;
            Eo23 = Eo23 * G2_23;
        }
    }

    const v2f den01 = de01 + do01, den23 = de23 + do23;
    const v2f num01 = ne01 + no01, num23 = ne23 + no23;

    const float wo = opw[0], bo = opb[0];
    const int rbase = blk * BSZ + 4 * lane;
    out[(size_t)(rbase + 0) * NN + n] = fmaf(num01.x / den01.x, wo, bo);
    out[(size_t)(rbase + 1) * NN + n] = fmaf(num01.y / den01.y, wo, bo);
    out[(size_t)(rbase + 2) * NN + n] = fmaf(num23.x / den23.x, wo, bo);
    out[(size_t)(rbase + 3) * NN + n] = fmaf(num23.y / den23.y, wo, bo);
}

extern "C" void kernel_launch(void* const* d_in, const int* in_sizes, int n_in,
                              void* d_out, int out_size, void* d_ws, size_t ws_size,
                              hipStream_t stream) {
    const float* q   = (const float*)d_in[0];
    const float* k   = (const float*)d_in[1];
    const float* v   = (const float*)d_in[2];
    const float* ipw = (const float*)d_in[3];
    const float* ipb = (const float*)d_in[4];
    const float* opw = (const float*)d_in[5];
    const float* opb = (const float*)d_in[6];
    float* out = (float*)d_out;
    float* ws  = (float*)d_ws;   // needs 3*L*N*4 = 12.6 MB

    proj_transpose_kernel<<<dim3(LL / 32), dim3(256), 0, stream>>>(q, k, v, ipw, ipb, ws);
    attn_kernel<<<dim3(NBLK * NN), dim3(64), 0, stream>>>(ws, opw, opb, out);
}